// Round 10
// baseline (67.008 us; speedup 1.0000x reference)
//
#include <hip/hip_runtime.h>

// ACT-R activation recurrence — single-barrier spine + off-chain broadcast.
// s_i = sum_{j<i} ((t_i-t_j)*H)^(-decay_j),  decay_j = w0 + w1*s_j  (s_0=0)
// (reference's max(diff*H,1) never binds: min gap 0.05 days * 2160 = 108)
// out[i-1,b] = sigmoid((ln(s_i)-TAU)/S), i=1..L-1.
//
// Identity: diff^(-decay_j) = exp2(q_ij*alpha_j), q_ij = -w1*log2(diff_ij),
// alpha = s + w0/w1; masked q = -1e30 -> term 0.
//
// R10 spine: sigma_j = P_j + T_j, T_j = exp2(qd_j * sigma_{j-1}).
//  - vector q-table masks j >= l-1 (subdiagonal excluded); qd[] carries it.
//  - P_{j+1}, qd_{j+1} prefetched via readlane one step EARLY (off-chain);
//    chain = mul -> exp2 -> add (~22 cyc/link vs ~90 with on-chain readlane).
//  - cndmask folds sigma_j back into lane j's alpha.
// One barrier per phase: wave0 computes the k-1 -> k strip from its own
// registers (t/dec of block k-1 live in lanes from the previous chain).
// Far tiles (r-c>=2): Chebyshev-8 per tile (R9), no atomics needed.

constexpr int   L  = 1024;
constexpr int   B  = 256;
constexpr int   T  = 64;
constexpr int   NT = 1024;   // 16 waves

constexpr float H_CONST = 86400.0f * 0.025f;   // 2160
constexpr float TAU_C   = -0.704205679427144f;
constexpr float S_C     = 0.254893976981164f;
constexpr float LN2     = 0.69314718055994530942f;
constexpr float LOG2E   = 1.4426950408889634074f;
constexpr float BIGNEG  = -1e30f;

// cos(k*pi/16)
constexpr float CC1 = 0.98078528040323044913f;
constexpr float CC2 = 0.92387953251128675613f;
constexpr float CC3 = 0.83146961230254523708f;
constexpr float CC4 = 0.70710678118654752440f;
constexpr float CC5 = 0.55557023301960222474f;
constexpr float CC6 = 0.38268343236508977173f;
constexpr float CC7 = 0.19509032201612826785f;

__device__ static const float UNODE[8] =
  { CC1, CC3, CC5, CC7, -CC7, -CC5, -CC3, -CC1 };

typedef float f32x4 __attribute__((ext_vector_type(4)));

__device__ __forceinline__ float flog2(float x) { return __builtin_amdgcn_logf(x); }
__device__ __forceinline__ float fexp2(float x) { return __builtin_amdgcn_exp2f(x); }
__device__ __forceinline__ float rdlane(float v, int l) {
    return __uint_as_float(__builtin_amdgcn_readlane(__float_as_uint(v), l));
}

#define LOADCH(p0, p1, p2, p3, c)                                   \
    p0 = *(const f32x4*)(qb + 4 * ((4 * (c) + 0) ^ xk));            \
    p1 = *(const f32x4*)(qb + 4 * ((4 * (c) + 1) ^ xk));            \
    p2 = *(const f32x4*)(qb + 4 * ((4 * (c) + 2) ^ xk));            \
    p3 = *(const f32x4*)(qb + 4 * ((4 * (c) + 3) ^ xk));

#define KEEP4(a, b, c, d) \
    asm volatile("" : "+v"(a), "+v"(b), "+v"(c), "+v"(d));

// one chain step at index J (J = 1..62): chain = mul->exp2->add; the two
// readlanes prefetch step J+1's scalars and sit OFF the chain.
#define STEPX(qe, J) {                                  \
    const float Tt = fexp2(sQ * sig);                   \
    sig = sP + Tt;                                      \
    sP  = rdlane(alpha, ((J) + 1) & 63);                \
    sQ  = rdlane(qdv,   ((J) + 1) & 63);                \
    alpha += fexp2((qe) * sig);                         \
    alpha = (lane == (J)) ? sig : alpha; }

#define STEP4(qv, J) \
    STEPX(qv.x, J) STEPX(qv.y, (J)+1) STEPX(qv.z, (J)+2) STEPX(qv.w, (J)+3)

__global__ __launch_bounds__(NT)
void actr_kernel(const float* __restrict__ sp, const float* __restrict__ w,
                 float* __restrict__ out)
{
    __shared__ float  tH[L];
    __shared__ float  acc[L];        // far-field partial sums
    __shared__ float2 col[L];        // finalized columns {t_j, -decay_j}
    __shared__ float  qT[2][T * T];  // triangle q (subdiag MASKED), swizzled
    __shared__ float  qd2[2][T];     // true subdiagonal q per row

    // XCD write-coalescing: blocks sharing an out cache line land on one XCD
    const int bid  = blockIdx.x;
    const int b    = (bid & 7) * 32 + (bid >> 3);
    const int tid  = threadIdx.x;
    const int lane = tid & 63;
    const int wv   = tid >> 6;
    const float w0  = w[0];
    const float w1  = w[1];
    const float CSH = w0 / w1;

    for (int i = tid; i < L; i += NT) {
        tH[i]  = sp[i * B + b] * H_CONST;
        acc[i] = 0.0f;
    }
    __syncthreads();

    // prologue: build qT[0]/qd2[0] for block 0
    for (int f = tid; f < T * T; f += NT) {
        const int j = f & 63, l2 = f >> 6;
        const float val = -w1 * flog2(tH[l2] - tH[j]);   // NaN for j>=l2, unused
        qT[0][l2 * 64 + (j ^ (4 * (l2 & 15)))] = (j <= l2 - 2) ? val : BIGNEG;
        if (j == l2 - 1) qd2[0][l2] = val;
    }
    __syncthreads();

    float my_t = (wv == 0) ? tH[lane] : 0.0f;   // block-0 row time (carried)
    float tp = 0.0f, dp = 0.0f;                 // block k-1 {t, -decay} in lanes

    for (int k = 0; k < L / T; ++k) {
        const int I0 = k * T;
        const int xk = lane & 15;
        const float* qb = &qT[k & 1][lane * 64];

        if (wv == 0) {
            // issue all LDS loads first; ownstrip (register-only) hides them
            f32x4 q0, q1, q2, q3, q4, q5, q6, q7, q8, q9, qA, qB, qC, qD, qE, qF;
            LOADCH(q0, q1, q2, q3, 0)
            LOADCH(q4, q5, q6, q7, 1)
            LOADCH(q8, q9, qA, qB, 2)
            LOADCH(qC, qD, qE, qF, 3)
            float qdv   = qd2[k & 1][lane];
            float acc_r = acc[I0 + lane];
            float tnext = tH[(I0 + 64 + lane) & (L - 1)];

            // ownstrip: cols k-1 (regs) -> own row, 4 partial accumulators
            float strip = 0.0f;
            if (k > 0) {
                float s0 = 0.f, s1 = 0.f, s2 = 0.f, s3 = 0.f;
                #pragma unroll
                for (int j = 0; j < 64; j += 4) {
                    s0 += fexp2(rdlane(dp, j    ) * flog2(my_t - rdlane(tp, j    )));
                    s1 += fexp2(rdlane(dp, j + 1) * flog2(my_t - rdlane(tp, j + 1)));
                    s2 += fexp2(rdlane(dp, j + 2) * flog2(my_t - rdlane(tp, j + 2)));
                    s3 += fexp2(rdlane(dp, j + 3) * flog2(my_t - rdlane(tp, j + 3)));
                }
                strip = (s0 + s1) + (s2 + s3);
            }
            KEEP4(q0, q1, q2, q3)
            KEEP4(q4, q5, q6, q7)
            KEEP4(q8, q9, qA, qB)
            KEEP4(qC, qD, qE, qF)
            asm volatile("" : "+v"(qdv), "+v"(acc_r));

            float alpha = acc_r + strip + CSH;
            __builtin_amdgcn_s_setprio(1);
            // chain: sigma_j = P_j + exp2(qd_j * sigma_{j-1})
            float sig = rdlane(alpha, 0);
            float sP  = rdlane(alpha, 1);
            float sQ  = rdlane(qdv, 1);
            alpha += fexp2(q0.x * sig);           // j=0 update (lanes >= 2)
            STEPX(q0.y,  1) STEPX(q0.z,  2) STEPX(q0.w,  3)
            STEP4(q1,  4) STEP4(q2,  8) STEP4(q3, 12)
            STEP4(q4, 16) STEP4(q5, 20) STEP4(q6, 24) STEP4(q7, 28)
            STEP4(q8, 32) STEP4(q9, 36) STEP4(qA, 40) STEP4(qB, 44)
            STEP4(qC, 48) STEP4(qD, 52) STEP4(qE, 56)
            STEPX(qF.x, 60) STEPX(qF.y, 61) STEPX(qF.z, 62)
            {   // last step j=63: no vector update needed (no lanes >= 65)
                const float Tt = fexp2(sQ * sig);
                sig = sP + Tt;
                alpha = (lane == 63) ? sig : alpha;
            }
            __builtin_amdgcn_s_setprio(0);

            // epilogue: finalize column, output, carry regs for next ownstrip
            const int r = I0 + lane;
            dp = -w1 * alpha;                      // -decay_r
            col[r] = make_float2(my_t, dp);
            if (r > 0) {
                const float act = flog2(alpha - CSH) * LN2;     // ln(s_r)
                const float e   = fexp2((TAU_C - act) * (LOG2E / S_C));
                out[(r - 1) * B + b] = 1.0f / (1.0f + e);
            }
            tp = my_t;
            my_t = tnext;
        } else {
            // far tile (r, k-1), r = k + wv, via Chebyshev-8 (reads col k-1
            // finalized last segment, behind the barrier)
            if (k >= 1 && wv <= 15 - k) {
                const int r  = k + wv;
                const int m  = lane >> 3;       // node index
                const int g  = lane & 7;        // col group
                const float At  = tH[r * 64];
                const float Bt  = tH[r * 64 + 63];
                const float mid = 0.5f * (At + Bt);
                const float hf  = 0.5f * (Bt - At);
                const float xm  = fmaf(hf, UNODE[m], mid);
                const float2* cb = &col[(k - 1) * 64 + g * 8];
                float gm = 0.0f;
                #pragma unroll
                for (int jj = 0; jj < 8; ++jj) {
                    const float2 cj = cb[jj];
                    gm += fexp2(cj.y * flog2(xm - cj.x));
                }
                gm += __shfl_xor(gm, 1);
                gm += __shfl_xor(gm, 2);
                gm += __shfl_xor(gm, 4);
                const float g0 = rdlane(gm,  0), g1 = rdlane(gm,  8);
                const float g2 = rdlane(gm, 16), g3 = rdlane(gm, 24);
                const float g4 = rdlane(gm, 32), g5 = rdlane(gm, 40);
                const float g6 = rdlane(gm, 48), g7 = rdlane(gm, 56);
                const float s0 = g0 + g7, s1 = g1 + g6, s2 = g2 + g5, s3 = g3 + g4;
                const float d0 = g0 - g7, d1 = g1 - g6, d2 = g2 - g5, d3 = g3 - g4;
                const float a0 = 0.125f * (s0 + s1 + s2 + s3);
                const float a2 = 0.25f * (CC2 * (s0 - s3) + CC6 * (s1 - s2));
                const float a4 = 0.25f * CC4 * (s0 - s1 - s2 + s3);
                const float a6 = 0.25f * (CC6 * (s0 - s3) - CC2 * (s1 - s2));
                const float a1 = 0.25f * (CC1*d0 + CC3*d1 + CC5*d2 + CC7*d3);
                const float a3 = 0.25f * (CC3*d0 - CC7*d1 - CC1*d2 - CC5*d3);
                const float a5 = 0.25f * (CC5*d0 - CC1*d1 + CC7*d2 + CC3*d3);
                const float a7 = 0.25f * (CC7*d0 - CC5*d1 + CC3*d2 - CC1*d3);
                const int   i  = r * 64 + lane;
                const float u  = (tH[i] - mid) * __builtin_amdgcn_rcpf(hf);
                const float u2 = u + u;
                float bk1 = a7;
                float bk  = fmaf(u2, a7, a6);
                float tt;
                tt = fmaf(u2, bk, a5) - bk1; bk1 = bk; bk = tt;
                tt = fmaf(u2, bk, a4) - bk1; bk1 = bk; bk = tt;
                tt = fmaf(u2, bk, a3) - bk1; bk1 = bk; bk = tt;
                tt = fmaf(u2, bk, a2) - bk1; bk1 = bk; bk = tt;
                tt = fmaf(u2, bk, a1) - bk1; bk1 = bk; bk = tt;
                const float p = fmaf(u, bk, a0) - bk1;
                acc[i] += p;                    // unique row per wave: no atomics
            }
            // build next block's qT/qd (timestamps only), 15 waves
            if (k < L / T - 1) {
                const int I1 = I0 + T;
                float* qn = &qT[(k + 1) & 1][0];
                const float vt = tH[I1 + lane];
                #pragma unroll
                for (int m2 = 0; m2 < 5; ++m2) {
                    const int l2 = (wv - 1) + 15 * m2;
                    if (l2 < 64) {
                        const float tl2 = rdlane(vt, l2);
                        const float val = -w1 * flog2(tl2 - vt);
                        qn[l2 * 64 + (lane ^ (4 * (l2 & 15)))] =
                            (lane <= l2 - 2) ? val : BIGNEG;
                        if (lane == l2 - 1) qd2[(k + 1) & 1][l2] = val;
                    }
                }
            }
        }
        __syncthreads();
    }
}

extern "C" void kernel_launch(void* const* d_in, const int* in_sizes, int n_in,
                              void* d_out, int out_size, void* d_ws, size_t ws_size,
                              hipStream_t stream) {
    const float* sp = (const float*)d_in[0];
    const float* w  = (const float*)d_in[1];
    float* out      = (float*)d_out;
    actr_kernel<<<dim3(B), dim3(NT), 0, stream>>>(sp, w, out);
}

// Round 11
// 52.557 us; speedup vs baseline: 1.2750x; 1.2750x over previous
//
#include <hip/hip_runtime.h>

// ACT-R activation recurrence — R9 structure + off-chain-subdiagonal chain.
// s_i = sum_{j<i} ((t_i-t_j)*H)^(-decay_j),  decay_j = w0 + w1*s_j  (s_0=0)
// (reference's max(diff*H,1) never binds: min gap 0.05 days * 2160 = 108)
// out[i-1,b] = sigmoid((ln(s_i)-TAU)/S), i=1..L-1.
//
// Identity: diff^(-decay_j) = exp2(q_ij*alpha_j), q_ij = -w1*log2(diff_ij),
// alpha = s + w0/w1 > 0; masked q = -1e30 -> exp2(-1e30*alpha) = 0.
//
// Phase k (two barriers, as R9 — known-good):
//  seg 1: wave0 pre-loads q-table into regs (pinned); ALL 1024 threads run the
//         strip (cols k-1 -> block-k rows, 16 thr/row).
//  seg 2: wave0 runs the triangle chain; waves 1..15 run ONE Chebyshev-8 far
//         tile each (r = k+wv, c = k-1) + build next q-table.
// R11 chain (the only change vs R9): sigma_j = P_j + exp2(qd_j*sigma_{j-1}).
// Vector q masks j >= l-1; subdiagonal lives in qd[]. P_{j+1}/qd_{j+1} are
// readlane-prefetched one step early (OFF the chain), so the serial path is
// mul -> exp2 -> add (~16-20 cyc) instead of add -> readlane -> mul -> exp2.

constexpr int   L  = 1024;
constexpr int   B  = 256;
constexpr int   T  = 64;
constexpr int   NT = 1024;   // 16 waves

constexpr float H_CONST = 86400.0f * 0.025f;   // 2160
constexpr float TAU_C   = -0.704205679427144f;
constexpr float S_C     = 0.254893976981164f;
constexpr float LN2     = 0.69314718055994530942f;
constexpr float LOG2E   = 1.4426950408889634074f;
constexpr float BIGNEG  = -1e30f;

// cos(k*pi/16)
constexpr float CC1 = 0.98078528040323044913f;
constexpr float CC2 = 0.92387953251128675613f;
constexpr float CC3 = 0.83146961230254523708f;
constexpr float CC4 = 0.70710678118654752440f;
constexpr float CC5 = 0.55557023301960222474f;
constexpr float CC6 = 0.38268343236508977173f;
constexpr float CC7 = 0.19509032201612826785f;

__device__ static const float UNODE[8] =
  { CC1, CC3, CC5, CC7, -CC7, -CC5, -CC3, -CC1 };

typedef float f32x4 __attribute__((ext_vector_type(4)));

__device__ __forceinline__ float flog2(float x) { return __builtin_amdgcn_logf(x); }
__device__ __forceinline__ float fexp2(float x) { return __builtin_amdgcn_exp2f(x); }
__device__ __forceinline__ float rdlane(float v, int l) {
    return __uint_as_float(__builtin_amdgcn_readlane(__float_as_uint(v), l));
}

#define LOADCH(p0, p1, p2, p3, c)                                   \
    p0 = *(const f32x4*)(qb + 4 * ((4 * (c) + 0) ^ xk));            \
    p1 = *(const f32x4*)(qb + 4 * ((4 * (c) + 1) ^ xk));            \
    p2 = *(const f32x4*)(qb + 4 * ((4 * (c) + 2) ^ xk));            \
    p3 = *(const f32x4*)(qb + 4 * ((4 * (c) + 3) ^ xk));

#define KEEP4(a, b, c, d) \
    asm volatile("" : "+v"(a), "+v"(b), "+v"(c), "+v"(d));

// chain step J (1..62): serial path = mul->exp2->add; readlanes prefetch
// step J+1's scalars off-chain; cndmask folds sigma_J into lane J.
#define STEPX(qe, J) {                                  \
    const float Tt = fexp2(sQ * sig);                   \
    sig = sP + Tt;                                      \
    sP  = rdlane(alpha, ((J) + 1) & 63);                \
    sQ  = rdlane(qdv,   ((J) + 1) & 63);                \
    alpha += fexp2((qe) * sig);                         \
    alpha = (lane == (J)) ? sig : alpha; }

#define STEP4(qv, J) \
    STEPX(qv.x, J) STEPX(qv.y, (J)+1) STEPX(qv.z, (J)+2) STEPX(qv.w, (J)+3)

__global__ __launch_bounds__(NT)
void actr_kernel(const float* __restrict__ sp, const float* __restrict__ w,
                 float* __restrict__ out)
{
    __shared__ float  tH[L];
    __shared__ float  acc[L];        // far-field partial sums
    __shared__ float2 col[L];        // finalized columns {t_j, -decay_j}
    __shared__ float  qT[2][T * T];  // triangle q (subdiag masked), swizzled
    __shared__ float  qd2[2][T];     // subdiagonal q per row
    __shared__ float  stripsum[T];

    // XCD write-coalescing: blocks sharing an out cache line -> same XCD
    const int bid  = blockIdx.x;
    const int b    = (bid & 7) * 32 + (bid >> 3);
    const int tid  = threadIdx.x;
    const int lane = tid & 63;
    const int wv   = tid >> 6;
    const float w0  = w[0];
    const float w1  = w[1];
    const float CSH = w0 / w1;

    for (int i = tid; i < L; i += NT) {
        tH[i]  = sp[i * B + b] * H_CONST;
        acc[i] = 0.0f;
    }
    if (tid < T) stripsum[tid] = 0.0f;
    if (tid == 0) { qd2[0][0] = 0.0f; qd2[1][0] = 0.0f; }
    __syncthreads();

    // prologue: build qT[0]/qd2[0] for block 0
    for (int f = tid; f < T * T; f += NT) {
        const int j = f & 63, l2 = f >> 6;
        const float val = -w1 * flog2(tH[l2] - tH[j]);   // NaN for j>=l2 unused
        qT[0][l2 * 64 + (j ^ (4 * (l2 & 15)))] = (j <= l2 - 2) ? val : BIGNEG;
        if (j == l2 - 1) qd2[0][l2] = val;
    }
    __syncthreads();

    for (int k = 0; k < L / T; ++k) {
        const int I0 = k * T;
        const int xk = lane & 15;
        const float* qb = &qT[k & 1][lane * 64];

        f32x4 q0, q1, q2, q3, q4, q5, q6, q7, q8, q9, qA, qB, qC, qD, qE, qF;
        float qdv = 0.0f, acc_r = 0.0f;
        if (wv == 0) {
            LOADCH(q0, q1, q2, q3, 0)
            LOADCH(q4, q5, q6, q7, 1)
            LOADCH(q8, q9, qA, qB, 2)
            LOADCH(qC, qD, qE, qF, 3)
            qdv   = qd2[k & 1][lane];
            acc_r = acc[I0 + lane];
            KEEP4(q0, q1, q2, q3)
            KEEP4(q4, q5, q6, q7)
            KEEP4(q8, q9, qA, qB)
            KEEP4(qC, qD, qE, qF)
            asm volatile("" : "+v"(qdv), "+v"(acc_r));
        }

        // strip: cols k-1 -> block-k rows; all 1024 threads, 16/row
        if (k > 0) {
            const int rl = tid >> 4, c = tid & 15;
            const float my_t = tH[I0 + rl];
            const float2* cb = &col[I0 - T];
            float p = 0.0f;
            #pragma unroll
            for (int uu = 0; uu < 4; ++uu) {
                const float2 cj = cb[c + 16 * uu];
                p += fexp2(cj.y * flog2(my_t - cj.x));
            }
            p += __shfl_xor(p, 1);
            p += __shfl_xor(p, 2);
            p += __shfl_xor(p, 4);
            p += __shfl_xor(p, 8);
            if (c == 0) stripsum[rl] = p;
        }
        __syncthreads();

        if (wv == 0) {
            // serial triangle: off-chain-subdiagonal recurrence
            float alpha = acc_r + stripsum[lane] + CSH;
            __builtin_amdgcn_s_setprio(1);
            float sig = rdlane(alpha, 0);
            float sP  = rdlane(alpha, 1);
            float sQ  = rdlane(qdv, 1);
            alpha += fexp2(q0.x * sig);           // j=0 vector update
            STEPX(q0.y,  1) STEPX(q0.z,  2) STEPX(q0.w,  3)
            STEP4(q1,  4) STEP4(q2,  8) STEP4(q3, 12)
            STEP4(q4, 16) STEP4(q5, 20) STEP4(q6, 24) STEP4(q7, 28)
            STEP4(q8, 32) STEP4(q9, 36) STEP4(qA, 40) STEP4(qB, 44)
            STEP4(qC, 48) STEP4(qD, 52) STEP4(qE, 56)
            STEPX(qF.x, 60) STEPX(qF.y, 61) STEPX(qF.z, 62)
            {   // j=63: no prefetch, no vector update needed
                const float Tt = fexp2(sQ * sig);
                sig = sP + Tt;
                alpha = (lane == 63) ? sig : alpha;
            }
            __builtin_amdgcn_s_setprio(0);

            const int r = I0 + lane;
            col[r] = make_float2(tH[r], -w1 * alpha);
            if (r > 0) {
                const float act = flog2(alpha - CSH) * LN2;     // ln(s_r)
                const float e   = fexp2((TAU_C - act) * (LOG2E / S_C));
                out[(r - 1) * B + b] = 1.0f / (1.0f + e);
            }
        } else {
            // far tile (r, k-1), r = k + wv, via Chebyshev-8
            if (k >= 1 && wv <= 15 - k) {
                const int r  = k + wv;
                const int m  = lane >> 3;       // node index
                const int g  = lane & 7;        // col group
                const float At  = tH[r * 64];
                const float Bt  = tH[r * 64 + 63];
                const float mid = 0.5f * (At + Bt);
                const float hf  = 0.5f * (Bt - At);
                const float xm  = fmaf(hf, UNODE[m], mid);
                const float2* cb = &col[(k - 1) * 64 + g * 8];
                float gm = 0.0f;
                #pragma unroll
                for (int jj = 0; jj < 8; ++jj) {
                    const float2 cj = cb[jj];
                    gm += fexp2(cj.y * flog2(xm - cj.x));
                }
                gm += __shfl_xor(gm, 1);
                gm += __shfl_xor(gm, 2);
                gm += __shfl_xor(gm, 4);
                const float g0 = rdlane(gm,  0), g1 = rdlane(gm,  8);
                const float g2 = rdlane(gm, 16), g3 = rdlane(gm, 24);
                const float g4 = rdlane(gm, 32), g5 = rdlane(gm, 40);
                const float g6 = rdlane(gm, 48), g7 = rdlane(gm, 56);
                const float s0 = g0 + g7, s1 = g1 + g6, s2 = g2 + g5, s3 = g3 + g4;
                const float d0 = g0 - g7, d1 = g1 - g6, d2 = g2 - g5, d3 = g3 - g4;
                const float a0 = 0.125f * (s0 + s1 + s2 + s3);
                const float a2 = 0.25f * (CC2 * (s0 - s3) + CC6 * (s1 - s2));
                const float a4 = 0.25f * CC4 * (s0 - s1 - s2 + s3);
                const float a6 = 0.25f * (CC6 * (s0 - s3) - CC2 * (s1 - s2));
                const float a1 = 0.25f * (CC1*d0 + CC3*d1 + CC5*d2 + CC7*d3);
                const float a3 = 0.25f * (CC3*d0 - CC7*d1 - CC1*d2 - CC5*d3);
                const float a5 = 0.25f * (CC5*d0 - CC1*d1 + CC7*d2 + CC3*d3);
                const float a7 = 0.25f * (CC7*d0 - CC5*d1 + CC3*d2 - CC1*d3);
                const int   i  = r * 64 + lane;
                const float u  = (tH[i] - mid) * __builtin_amdgcn_rcpf(hf);
                const float u2 = u + u;
                float bk1 = a7;
                float bk  = fmaf(u2, a7, a6);
                float tt;
                tt = fmaf(u2, bk, a5) - bk1; bk1 = bk; bk = tt;
                tt = fmaf(u2, bk, a4) - bk1; bk1 = bk; bk = tt;
                tt = fmaf(u2, bk, a3) - bk1; bk1 = bk; bk = tt;
                tt = fmaf(u2, bk, a2) - bk1; bk1 = bk; bk = tt;
                tt = fmaf(u2, bk, a1) - bk1; bk1 = bk; bk = tt;
                const float p = fmaf(u, bk, a0) - bk1;
                acc[i] += p;                    // unique row per wave: no atomics
            }
            // build next block's qT/qd2 (timestamps only), 15 waves
            if (k < L / T - 1) {
                const int I1 = I0 + T;
                float* qn = &qT[(k + 1) & 1][0];
                const float vt = tH[I1 + lane];
                #pragma unroll
                for (int m2 = 0; m2 < 5; ++m2) {
                    const int l2 = (wv - 1) + 15 * m2;
                    if (l2 < 64) {
                        const float tl2 = rdlane(vt, l2);
                        const float val = -w1 * flog2(tl2 - vt);
                        qn[l2 * 64 + (lane ^ (4 * (l2 & 15)))] =
                            (lane <= l2 - 2) ? val : BIGNEG;
                        if (lane == l2 - 1) qd2[(k + 1) & 1][l2] = val;
                    }
                }
            }
        }
        __syncthreads();
    }
}

extern "C" void kernel_launch(void* const* d_in, const int* in_sizes, int n_in,
                              void* d_out, int out_size, void* d_ws, size_t ws_size,
                              hipStream_t stream) {
    const float* sp = (const float*)d_in[0];
    const float* w  = (const float*)d_in[1];
    float* out      = (float*)d_out;
    actr_kernel<<<dim3(B), dim3(NT), 0, stream>>>(sp, w, out);
}

// Round 12
// 49.927 us; speedup vs baseline: 1.3421x; 1.0527x over previous
//
#include <hip/hip_runtime.h>

// ACT-R activation recurrence — Chebyshev far-field + seg2-isolated chain SIMD.
// s_i = sum_{j<i} ((t_i-t_j)*H)^(-decay_j),  decay_j = w0 + w1*s_j  (s_0=0)
// (reference's max(diff*H,1) never binds: min gap 0.05 days * 2160 = 108)
// out[i-1,b] = sigmoid((ln(s_i)-TAU)/S), i=1..L-1.
//
// Identity: diff^(-decay_j) = exp2(q_ij*alpha_j), q_ij = -w1*log2(diff_ij),
// alpha = s + w0/w1 > 0; masked q = -1e30 -> term 0.
//
// Phase k, two barriers:
//  seg1: wave0 pre-loads block-k q-table into pinned regs; ALL 16 waves run
//        the strip (cols k-1 -> block-k rows, 16 thr/row).
//  seg2: wave0 runs the 64-step serial chain (R9 form: rdlane->mul->exp2->add)
//        ALONE on SIMD0 — waves 4/8/12 idle here so the chain gets every
//        issue slot. 12 worker waves (wv%4!=0) run Chebyshev-8 far tiles
//        (col k-1, rows k+1..15; front-loaded, no collisions -> no atomics),
//        build the next q-table, and one computes block k-1's outputs from
//        stashed alpha (epilogue off the chain's critical path).

constexpr int   L  = 1024;
constexpr int   B  = 256;
constexpr int   T  = 64;
constexpr int   NT = 1024;   // 16 waves

constexpr float H_CONST = 86400.0f * 0.025f;   // 2160
constexpr float TAU_C   = -0.704205679427144f;
constexpr float S_C     = 0.254893976981164f;
constexpr float LN2     = 0.69314718055994530942f;
constexpr float LOG2E   = 1.4426950408889634074f;
constexpr float BIGNEG  = -1e30f;

// cos(k*pi/16)
constexpr float CC1 = 0.98078528040323044913f;
constexpr float CC2 = 0.92387953251128675613f;
constexpr float CC3 = 0.83146961230254523708f;
constexpr float CC4 = 0.70710678118654752440f;
constexpr float CC5 = 0.55557023301960222474f;
constexpr float CC6 = 0.38268343236508977173f;
constexpr float CC7 = 0.19509032201612826785f;

__device__ static const float UNODE[8] =
  { CC1, CC3, CC5, CC7, -CC7, -CC5, -CC3, -CC1 };

typedef float f32x4 __attribute__((ext_vector_type(4)));

__device__ __forceinline__ float flog2(float x) { return __builtin_amdgcn_logf(x); }
__device__ __forceinline__ float fexp2(float x) { return __builtin_amdgcn_exp2f(x); }
__device__ __forceinline__ float rdlane(float v, int l) {
    return __uint_as_float(__builtin_amdgcn_readlane(__float_as_uint(v), l));
}

#define LOADCH(p0, p1, p2, p3, c)                                   \
    p0 = *(const f32x4*)(qb + 4 * ((4 * (c) + 0) ^ xk));            \
    p1 = *(const f32x4*)(qb + 4 * ((4 * (c) + 1) ^ xk));            \
    p2 = *(const f32x4*)(qb + 4 * ((4 * (c) + 2) ^ xk));            \
    p3 = *(const f32x4*)(qb + 4 * ((4 * (c) + 3) ^ xk));

#define KEEP4(a, b, c, d) \
    asm volatile("" : "+v"(a), "+v"(b), "+v"(c), "+v"(d));

#define RUN4(qv, J)                                                  \
    { float sg;                                                      \
      sg = rdlane(alpha, (J) + 0); alpha += fexp2(qv.x * sg);        \
      sg = rdlane(alpha, (J) + 1); alpha += fexp2(qv.y * sg);        \
      sg = rdlane(alpha, (J) + 2); alpha += fexp2(qv.z * sg);        \
      sg = rdlane(alpha, (J) + 3); alpha += fexp2(qv.w * sg); }

__global__ __launch_bounds__(NT)
void actr_kernel(const float* __restrict__ sp, const float* __restrict__ w,
                 float* __restrict__ out)
{
    __shared__ float  tH[L];
    __shared__ float  acc[L];        // far-field partial sums
    __shared__ float2 col[L];        // finalized columns {t_j, -decay_j}
    __shared__ float  qT[2][T * T];  // triangle q (subdiag incl.), swizzled
    __shared__ float  stripsum[T];
    __shared__ float  alphaS[2][T];  // raw alpha per block (epilogue offload)

    // XCD write-coalescing: blocks sharing an out cache line -> same XCD
    const int bid  = blockIdx.x;
    const int b    = (bid & 7) * 32 + (bid >> 3);
    const int tid  = threadIdx.x;
    const int lane = tid & 63;
    const int wv   = tid >> 6;
    const bool isChain  = (wv == 0);
    const bool isWorker = (wv != 0) && ((wv & 3) != 0);  // 12 waves
    const int  pidx     = wv - 1 - (wv >> 2);            // 0..11 for workers
    const float w0  = w[0];
    const float w1  = w[1];
    const float CSH = w0 / w1;

    for (int i = tid; i < L; i += NT) {
        tH[i]  = sp[i * B + b] * H_CONST;
        acc[i] = 0.0f;
    }
    if (tid < T) stripsum[tid] = 0.0f;
    __syncthreads();

    // prologue: build qT[0] for block 0
    for (int f = tid; f < T * T; f += NT) {
        const int j = f & 63, l2 = f >> 6;
        const float q = (j < l2) ? (-w1 * flog2(tH[l2] - tH[j])) : BIGNEG;
        qT[0][l2 * 64 + (j ^ (4 * (l2 & 15)))] = q;
    }
    __syncthreads();

    for (int k = 0; k < L / T; ++k) {
        const int I0 = k * T;
        const int xk = lane & 15;
        const float* qb = &qT[k & 1][lane * 64];

        f32x4 q0, q1, q2, q3, q4, q5, q6, q7, q8, q9, qA, qB, qC, qD, qE, qF;
        float acc_r = 0.0f;
        if (isChain) {
            LOADCH(q0, q1, q2, q3, 0)
            LOADCH(q4, q5, q6, q7, 1)
            LOADCH(q8, q9, qA, qB, 2)
            LOADCH(qC, qD, qE, qF, 3)
            acc_r = acc[I0 + lane];
            KEEP4(q0, q1, q2, q3)
            KEEP4(q4, q5, q6, q7)
            KEEP4(q8, q9, qA, qB)
            KEEP4(qC, qD, qE, qF)
            asm volatile("" : "+v"(acc_r));
        }

        // seg1 strip: cols k-1 -> block-k rows; all 16 waves, 16 thr/row
        if (k > 0) {
            const int rl = tid >> 4, c = tid & 15;
            const float my_t = tH[I0 + rl];
            const float2* cb = &col[I0 - T];
            float p = 0.0f;
            #pragma unroll
            for (int uu = 0; uu < 4; ++uu) {
                const float2 cj = cb[c + 16 * uu];
                p += fexp2(cj.y * flog2(my_t - cj.x));
            }
            p += __shfl_xor(p, 1);
            p += __shfl_xor(p, 2);
            p += __shfl_xor(p, 4);
            p += __shfl_xor(p, 8);
            if (c == 0) stripsum[rl] = p;
        }
        __syncthreads();

        if (isChain) {
            // serial triangle — alone on SIMD0 during seg2
            float alpha = acc_r + stripsum[lane] + CSH;
            __builtin_amdgcn_s_setprio(1);
            RUN4(q0,  0) RUN4(q1,  4) RUN4(q2,  8) RUN4(q3, 12)
            RUN4(q4, 16) RUN4(q5, 20) RUN4(q6, 24) RUN4(q7, 28)
            RUN4(q8, 32) RUN4(q9, 36) RUN4(qA, 40) RUN4(qB, 44)
            RUN4(qC, 48) RUN4(qD, 52) RUN4(qE, 56) RUN4(qF, 60)
            __builtin_amdgcn_s_setprio(0);
            const int r = I0 + lane;
            col[r] = make_float2(tH[r], -w1 * alpha);
            alphaS[k & 1][lane] = alpha;
        } else if (isWorker) {
            // far tiles (r, k-1) via Chebyshev-8; front-loaded at phase k=c+1.
            // pidx 0..11 -> r = k+1+pidx; pidx 0,1 may carry r = k+13+pidx.
            if (k >= 1) {
                #pragma unroll
                for (int tt2 = 0; tt2 < 2; ++tt2) {
                    const int r = k + 1 + pidx + 12 * tt2;
                    if (r <= 15 && (tt2 == 0 || pidx + k <= 2)) {
                        const int m  = lane >> 3;       // node index
                        const int g  = lane & 7;        // col group
                        const float At  = tH[r * 64];
                        const float Bt  = tH[r * 64 + 63];
                        const float mid = 0.5f * (At + Bt);
                        const float hf  = 0.5f * (Bt - At);
                        const float xm  = fmaf(hf, UNODE[m], mid);
                        const float2* cb = &col[(k - 1) * 64 + g * 8];
                        float gm = 0.0f;
                        #pragma unroll
                        for (int jj = 0; jj < 8; ++jj) {
                            const float2 cj = cb[jj];
                            gm += fexp2(cj.y * flog2(xm - cj.x));
                        }
                        gm += __shfl_xor(gm, 1);
                        gm += __shfl_xor(gm, 2);
                        gm += __shfl_xor(gm, 4);
                        const float g0 = rdlane(gm,  0), g1 = rdlane(gm,  8);
                        const float g2 = rdlane(gm, 16), g3 = rdlane(gm, 24);
                        const float g4 = rdlane(gm, 32), g5 = rdlane(gm, 40);
                        const float g6 = rdlane(gm, 48), g7 = rdlane(gm, 56);
                        const float s0 = g0 + g7, s1 = g1 + g6;
                        const float s2 = g2 + g5, s3 = g3 + g4;
                        const float d0 = g0 - g7, d1 = g1 - g6;
                        const float d2 = g2 - g5, d3 = g3 - g4;
                        const float a0 = 0.125f * (s0 + s1 + s2 + s3);
                        const float a2 = 0.25f * (CC2 * (s0 - s3) + CC6 * (s1 - s2));
                        const float a4 = 0.25f * CC4 * (s0 - s1 - s2 + s3);
                        const float a6 = 0.25f * (CC6 * (s0 - s3) - CC2 * (s1 - s2));
                        const float a1 = 0.25f * (CC1*d0 + CC3*d1 + CC5*d2 + CC7*d3);
                        const float a3 = 0.25f * (CC3*d0 - CC7*d1 - CC1*d2 - CC5*d3);
                        const float a5 = 0.25f * (CC5*d0 - CC1*d1 + CC7*d2 + CC3*d3);
                        const float a7 = 0.25f * (CC7*d0 - CC5*d1 + CC3*d2 - CC1*d3);
                        const int   i  = r * 64 + lane;
                        const float u  = (tH[i] - mid) * __builtin_amdgcn_rcpf(hf);
                        const float u2 = u + u;
                        float bk1 = a7;
                        float bk  = fmaf(u2, a7, a6);
                        float t3;
                        t3 = fmaf(u2, bk, a5) - bk1; bk1 = bk; bk = t3;
                        t3 = fmaf(u2, bk, a4) - bk1; bk1 = bk; bk = t3;
                        t3 = fmaf(u2, bk, a3) - bk1; bk1 = bk; bk = t3;
                        t3 = fmaf(u2, bk, a2) - bk1; bk1 = bk; bk = t3;
                        t3 = fmaf(u2, bk, a1) - bk1; bk1 = bk; bk = t3;
                        acc[i] += fmaf(u, bk, a0) - bk1;   // unique rows
                    }
                }
            }
            // build next block's qT (timestamps only) over 12 workers
            if (k < L / T - 1) {
                const int I1 = I0 + T;
                float* qn = &qT[(k + 1) & 1][0];
                const float vt = tH[I1 + lane];
                #pragma unroll
                for (int m2 = 0; m2 < 6; ++m2) {
                    const int l2 = pidx + 12 * m2;
                    if (l2 < 64) {
                        const float tl2 = rdlane(vt, l2);
                        const float q = (lane < l2) ? (-w1 * flog2(tl2 - vt))
                                                    : BIGNEG;
                        qn[l2 * 64 + (lane ^ (4 * (l2 & 15)))] = q;
                    }
                }
            }
            // epilogue offload: outputs for block k-1 (alpha stashed last phase)
            if (pidx == 10 && k >= 1) {
                const int rr = (k - 1) * 64 + lane;
                if (rr > 0) {
                    const float alpha = alphaS[(k - 1) & 1][lane];
                    const float act = flog2(alpha - CSH) * LN2;     // ln(s)
                    const float e   = fexp2((TAU_C - act) * (LOG2E / S_C));
                    out[(rr - 1) * B + b] = 1.0f / (1.0f + e);
                }
            }
        }
        // waves 4, 8, 12 idle in seg2: SIMD0 belongs to the chain
        __syncthreads();
    }

    // outputs for the last block (k = 15)
    if (wv == 0) {
        const int rr = 960 + lane;
        const float alpha = alphaS[1][lane];
        const float act = flog2(alpha - CSH) * LN2;
        const float e   = fexp2((TAU_C - act) * (LOG2E / S_C));
        out[(rr - 1) * B + b] = 1.0f / (1.0f + e);
    }
}

extern "C" void kernel_launch(void* const* d_in, const int* in_sizes, int n_in,
                              void* d_out, int out_size, void* d_ws, size_t ws_size,
                              hipStream_t stream) {
    const float* sp = (const float*)d_in[0];
    const float* w  = (const float*)d_in[1];
    float* out      = (float*)d_out;
    actr_kernel<<<dim3(B), dim3(NT), 0, stream>>>(sp, w, out);
}

// Round 13
// 47.392 us; speedup vs baseline: 1.4139x; 1.0535x over previous
//
#include <hip/hip_runtime.h>

// ACT-R activation recurrence — barrier-free producer/consumer spine.
// s_i = sum_{j<i} ((t_i-t_j)*H)^(-decay_j),  decay_j = w0 + w1*s_j  (s_0=0)
// (reference's max(diff*H,1) never binds: min gap 0.05 days * 2160 = 108)
// out[i-1,b] = sigmoid((ln(s_i)-TAU)/S), i=1..L-1.
//
// Identity: diff^(-decay_j) = exp2(q_ij*alpha_j), q_ij = -w1*log2(diff_ij),
// alpha = s + w0/w1 > 0; masked q = -1e30 -> term 0.
//
// R13: R11 proved the serial chain is NOT latency-dominated; accounting says
// ~3k cyc/phase was barrier-convergence slack (2 full barriers x 16 waves in
// lockstep). This version has NO __syncthreads in the main loop:
//   wave 0 (chain): for k=0..15: spin DONE[k]==target -> load qT -> 64-step
//     chain -> write col -> set COLF[k] -> write outputs.
//   waves 1..7 (workers, p=wv-1): for c=0..14: spin COLF[c] ->
//     strip (c+1,c) exact (atomicAdd into acc) -> Chebyshev far tiles (r,c)
//     r=c+2+p, c+9+p -> build qT slot for block c+2 -> bump DONE counters.
// Release/acquire via same-wave DS ordering + compiler memory barriers.
// DONE targets: k=0: 0; k=1: 7 (strip); k>=2: (k-1) far + 7 strip + 7 build.

constexpr int   L  = 1024;
constexpr int   B  = 256;
constexpr int   T  = 64;
constexpr int   NT = 512;    // 8 waves: 1 chain + 7 workers

constexpr float H_CONST = 86400.0f * 0.025f;   // 2160
constexpr float TAU_C   = -0.704205679427144f;
constexpr float S_C     = 0.254893976981164f;
constexpr float LN2     = 0.69314718055994530942f;
constexpr float LOG2E   = 1.4426950408889634074f;
constexpr float BIGNEG  = -1e30f;

// cos(k*pi/16)
constexpr float CC1 = 0.98078528040323044913f;
constexpr float CC2 = 0.92387953251128675613f;
constexpr float CC3 = 0.83146961230254523708f;
constexpr float CC4 = 0.70710678118654752440f;
constexpr float CC5 = 0.55557023301960222474f;
constexpr float CC6 = 0.38268343236508977173f;
constexpr float CC7 = 0.19509032201612826785f;

__device__ static const float UNODE[8] =
  { CC1, CC3, CC5, CC7, -CC7, -CC5, -CC3, -CC1 };

typedef float f32x4 __attribute__((ext_vector_type(4)));

__device__ __forceinline__ float flog2(float x) { return __builtin_amdgcn_logf(x); }
__device__ __forceinline__ float fexp2(float x) { return __builtin_amdgcn_exp2f(x); }
__device__ __forceinline__ float rdlane(float v, int l) {
    return __uint_as_float(__builtin_amdgcn_readlane(__float_as_uint(v), l));
}

#define LOADCH(p0, p1, p2, p3, c)                                   \
    p0 = *(const f32x4*)(qb + 4 * ((4 * (c) + 0) ^ xk));            \
    p1 = *(const f32x4*)(qb + 4 * ((4 * (c) + 1) ^ xk));            \
    p2 = *(const f32x4*)(qb + 4 * ((4 * (c) + 2) ^ xk));            \
    p3 = *(const f32x4*)(qb + 4 * ((4 * (c) + 3) ^ xk));

#define KEEP4(a, b, c, d) \
    asm volatile("" : "+v"(a), "+v"(b), "+v"(c), "+v"(d));

#define RUN4(qv, J)                                                  \
    { float sg;                                                      \
      sg = rdlane(alpha, (J) + 0); alpha += fexp2(qv.x * sg);        \
      sg = rdlane(alpha, (J) + 1); alpha += fexp2(qv.y * sg);        \
      sg = rdlane(alpha, (J) + 2); alpha += fexp2(qv.z * sg);        \
      sg = rdlane(alpha, (J) + 3); alpha += fexp2(qv.w * sg); }

__global__ __launch_bounds__(NT)
void actr_kernel(const float* __restrict__ sp, const float* __restrict__ w,
                 float* __restrict__ out)
{
    __shared__ float  tH[L];
    __shared__ float  acc[L];        // strip + far partial sums (ds_add_f32)
    __shared__ float2 col[L];        // finalized columns {t_j, -decay_j}
    __shared__ float  qT[2][T * T];  // triangle q, swizzled, 2-slot rotation
    __shared__ int    COLF[16];      // col block k published
    __shared__ int    DONE[16];      // contribution counter per row block

    const int bid  = blockIdx.x;
    const int b    = (bid & 7) * 32 + (bid >> 3);   // XCD write-coalescing
    const int tid  = threadIdx.x;
    const int lane = tid & 63;
    const int wv   = tid >> 6;       // 0..7
    const float w0  = w[0];
    const float w1  = w[1];
    const float CSH = w0 / w1;

    for (int i = tid; i < L; i += NT) {
        tH[i]  = sp[i * B + b] * H_CONST;
        acc[i] = 0.0f;
    }
    if (tid < 16) { COLF[tid] = 0; DONE[tid] = 0; }
    __syncthreads();

    // prologue: build qT for blocks 0 and 1 (all 8 waves)
    for (int blk = 0; blk < 2; ++blk) {
        const int base = blk * 64;
        for (int f = tid; f < T * T; f += NT) {
            const int j = f & 63, l2 = f >> 6;
            const float q = (j < l2) ? (-w1 * flog2(tH[base + l2] - tH[base + j]))
                                     : BIGNEG;
            qT[blk][l2 * 64 + (j ^ (4 * (l2 & 15)))] = q;
        }
    }
    __syncthreads();    // last barrier — none in the main loop

    if (wv == 0) {
        // ================= chain wave =================
        volatile int* vDONE = DONE;
        const int xk = lane & 15;
        for (int k = 0; k < 16; ++k) {
            const int I0 = k * T;
            const int target = (k == 0) ? 0 : (k == 1) ? 7 : k + 13;
            while (vDONE[k] < target) __builtin_amdgcn_s_sleep(2);
            asm volatile("" ::: "memory");

            const float* qb = &qT[k & 1][lane * 64];
            f32x4 q0, q1, q2, q3, q4, q5, q6, q7, q8, q9, qA, qB, qC, qD, qE, qF;
            LOADCH(q0, q1, q2, q3, 0)
            LOADCH(q4, q5, q6, q7, 1)
            LOADCH(q8, q9, qA, qB, 2)
            LOADCH(qC, qD, qE, qF, 3)
            float acc_r = acc[I0 + lane];
            KEEP4(q0, q1, q2, q3)
            KEEP4(q4, q5, q6, q7)
            KEEP4(q8, q9, qA, qB)
            KEEP4(qC, qD, qE, qF)
            asm volatile("" : "+v"(acc_r));

            float alpha = acc_r + CSH;
            __builtin_amdgcn_s_setprio(1);
            RUN4(q0,  0) RUN4(q1,  4) RUN4(q2,  8) RUN4(q3, 12)
            RUN4(q4, 16) RUN4(q5, 20) RUN4(q6, 24) RUN4(q7, 28)
            RUN4(q8, 32) RUN4(q9, 36) RUN4(qA, 40) RUN4(qB, 44)
            RUN4(qC, 48) RUN4(qD, 52) RUN4(qE, 56) RUN4(qF, 60)
            __builtin_amdgcn_s_setprio(0);

            const int r = I0 + lane;
            col[r] = make_float2(tH[r], -w1 * alpha);
            asm volatile("" ::: "memory");
            if (lane == 0) atomicExch(&COLF[k], 1);   // release: col visible first

            if (r > 0) {   // outputs after the handoff — off workers' wait path
                const float act = flog2(alpha - CSH) * LN2;     // ln(s_r)
                const float e   = fexp2((TAU_C - act) * (LOG2E / S_C));
                out[(r - 1) * B + b] = 1.0f / (1.0f + e);
            }
        }
    } else {
        // ================= worker waves =================
        const int p = wv - 1;        // 0..6
        volatile int* vCOLF = COLF;
        for (int c = 0; c < 15; ++c) {
            while (vCOLF[c] == 0) __builtin_amdgcn_s_sleep(2);
            asm volatile("" ::: "memory");

            // --- strip (c+1, c): exact; 16 thr/row, 4 rows per rowgroup ---
            {
                const float2* cb = &col[c * 64];
                #pragma unroll
                for (int m = 0; m < 3; ++m) {
                    const int g = p + 7 * m;          // rowgroup 0..15
                    if (g < 16) {
                        const int rl = 4 * g + (lane >> 4);
                        const int c4 = lane & 15;
                        const float my_t = tH[(c + 1) * 64 + rl];
                        float s = 0.0f;
                        #pragma unroll
                        for (int u = 0; u < 4; ++u) {
                            const float2 cj = cb[c4 + 16 * u];
                            s += fexp2(cj.y * flog2(my_t - cj.x));
                        }
                        s += __shfl_xor(s, 1);
                        s += __shfl_xor(s, 2);
                        s += __shfl_xor(s, 4);
                        s += __shfl_xor(s, 8);
                        if (c4 == 0) atomicAdd(&acc[(c + 1) * 64 + rl], s);
                    }
                }
                asm volatile("" ::: "memory");
                if (lane == 0) atomicAdd(&DONE[c + 1], 1);
            }

            // --- far tiles (r, c) via Chebyshev-8: r = c+2+p, c+9+p ---
            #pragma unroll
            for (int t2 = 0; t2 < 2; ++t2) {
                const int r = c + 2 + p + 7 * t2;
                if (r <= 15) {
                    const int m  = lane >> 3;       // node index
                    const int g  = lane & 7;        // col group
                    const float At  = tH[r * 64];
                    const float Bt  = tH[r * 64 + 63];
                    const float mid = 0.5f * (At + Bt);
                    const float hf  = 0.5f * (Bt - At);
                    const float xm  = fmaf(hf, UNODE[m], mid);
                    const float2* cb = &col[c * 64 + g * 8];
                    float gm = 0.0f;
                    #pragma unroll
                    for (int jj = 0; jj < 8; ++jj) {
                        const float2 cj = cb[jj];
                        gm += fexp2(cj.y * flog2(xm - cj.x));
                    }
                    gm += __shfl_xor(gm, 1);
                    gm += __shfl_xor(gm, 2);
                    gm += __shfl_xor(gm, 4);
                    const float g0 = rdlane(gm,  0), g1 = rdlane(gm,  8);
                    const float g2 = rdlane(gm, 16), g3 = rdlane(gm, 24);
                    const float g4 = rdlane(gm, 32), g5 = rdlane(gm, 40);
                    const float g6 = rdlane(gm, 48), g7 = rdlane(gm, 56);
                    const float s0 = g0 + g7, s1 = g1 + g6;
                    const float s2 = g2 + g5, s3 = g3 + g4;
                    const float d0 = g0 - g7, d1 = g1 - g6;
                    const float d2 = g2 - g5, d3 = g3 - g4;
                    const float a0 = 0.125f * (s0 + s1 + s2 + s3);
                    const float a2 = 0.25f * (CC2 * (s0 - s3) + CC6 * (s1 - s2));
                    const float a4 = 0.25f * CC4 * (s0 - s1 - s2 + s3);
                    const float a6 = 0.25f * (CC6 * (s0 - s3) - CC2 * (s1 - s2));
                    const float a1 = 0.25f * (CC1*d0 + CC3*d1 + CC5*d2 + CC7*d3);
                    const float a3 = 0.25f * (CC3*d0 - CC7*d1 - CC1*d2 - CC5*d3);
                    const float a5 = 0.25f * (CC5*d0 - CC1*d1 + CC7*d2 + CC3*d3);
                    const float a7 = 0.25f * (CC7*d0 - CC5*d1 + CC3*d2 - CC1*d3);
                    const int   i  = r * 64 + lane;
                    const float u  = (tH[i] - mid) * __builtin_amdgcn_rcpf(hf);
                    const float u2 = u + u;
                    float bk1 = a7;
                    float bk  = fmaf(u2, a7, a6);
                    float t3;
                    t3 = fmaf(u2, bk, a5) - bk1; bk1 = bk; bk = t3;
                    t3 = fmaf(u2, bk, a4) - bk1; bk1 = bk; bk = t3;
                    t3 = fmaf(u2, bk, a3) - bk1; bk1 = bk; bk = t3;
                    t3 = fmaf(u2, bk, a2) - bk1; bk1 = bk; bk = t3;
                    t3 = fmaf(u2, bk, a1) - bk1; bk1 = bk; bk = t3;
                    atomicAdd(&acc[i], fmaf(u, bk, a0) - bk1);
                    asm volatile("" ::: "memory");
                    if (lane == 0) atomicAdd(&DONE[r], 1);
                }
            }

            // --- build qT for block c+2 (timestamps only) ---
            if (c <= 13) {
                const int blk  = c + 2;
                const int base = blk * 64;
                float* qn = &qT[blk & 1][0];
                const float vt = tH[base + lane];
                #pragma unroll
                for (int m2 = 0; m2 < 10; ++m2) {
                    const int l2 = p + 7 * m2;
                    if (l2 < 64) {
                        const float tl2 = rdlane(vt, l2);
                        const float q = (lane < l2) ? (-w1 * flog2(tl2 - vt))
                                                    : BIGNEG;
                        qn[l2 * 64 + (lane ^ (4 * (l2 & 15)))] = q;
                    }
                }
                asm volatile("" ::: "memory");
                if (lane == 0) atomicAdd(&DONE[blk], 1);
            }
        }
    }
}

extern "C" void kernel_launch(void* const* d_in, const int* in_sizes, int n_in,
                              void* d_out, int out_size, void* d_ws, size_t ws_size,
                              hipStream_t stream) {
    const float* sp = (const float*)d_in[0];
    const float* w  = (const float*)d_in[1];
    float* out      = (float*)d_out;
    actr_kernel<<<dim3(B), dim3(NT), 0, stream>>>(sp, w, out);
}